// Round 10
// baseline (1073.564 us; speedup 1.0000x reference)
//
#include <hip/hip_runtime.h>
#include <hip/hip_cooperative_groups.h>
#include <stdint.h>

namespace cg = cooperative_groups;

typedef unsigned long long u64;
typedef unsigned int u32;
typedef unsigned short u16;
typedef unsigned char u8;
typedef signed char s8;

// ---------------- workspace layout (bytes) ----------------
#define WS_STATS 0          // long long[2304]
#define WS_W1Q   20480      // u32[240]
#define WS_W2P   24576      // u64[432]
#define WS_W3P   28672      // u64[432]
#define WS_WFCP  32768      // u64[205]
#define WS_A2    40960      // u64[4096*154] ends 5,087,232
#define WS_P1    5087232    // u8[4096*8448] (stages 1-2); overlaid by P3 int[4096*1440] (stages 3-4)

// ---------------- d_out offsets (floats) ----------------
#define OUT_OFF 0
#define XB1_OFF 20480
#define XB2_OFF 8867840
#define XB3_OFF 39145472
#define FB_OFF  60379136

__device__ __forceinline__ float fsign(float v) {
    return (v > 0.0f) ? 1.0f : ((v < 0.0f) ? -1.0f : 0.0f);
}
__device__ __forceinline__ int sh16(int v, int h) {
    return h ? (v >> 16) : (int)(short)v;
}

__global__ __launch_bounds__(256, 4)
void kfull(const float* __restrict__ x,
           const float* __restrict__ w1, const float* __restrict__ g1, const float* __restrict__ b1,
           const float* __restrict__ w2, const float* __restrict__ g2, const float* __restrict__ b2,
           const float* __restrict__ w3, const float* __restrict__ g3, const float* __restrict__ b3,
           const float* __restrict__ wfc,
           float* __restrict__ dout,
           long long* __restrict__ stats,
           u32* __restrict__ W1Q, u64* __restrict__ W2P, u64* __restrict__ W3P,
           u64* __restrict__ WFCP, u64* __restrict__ A2,
           u8* P1g, int* P3i) {
    cg::grid_group grid = cg::this_grid();
    __shared__ char smem[21632];
    int2*  part = (int2*)smem;            // [256] @0..2048
    float* sc   = (float*)(smem + 2048);  // [48]
    float* sh   = (float*)(smem + 2240);  // [48]
    int t = threadIdx.x, blk = blockIdx.x;
    int nblk = gridDim.x;

    // ======== stage 0: pack weights + zero stats ========
    if (blk == 0) {
        if (t < 48) {
            u16 m1[9];
            #pragma unroll
            for (int p = 0; p < 9; ++p) {
                u16 m = 0;
                for (int c = 0; c < 12; ++c)
                    if (w1[t*108 + c*9 + p] > 0.0f) m |= (u16)(1u << c);
                m1[p] = m;
            }
            #pragma unroll
            for (int j = 0; j < 4; ++j)
                W1Q[t*5 + j] = (u32)m1[2*j] | ((u32)m1[2*j+1] << 16);
            W1Q[t*5 + 4] = (u32)m1[8];
        }
        for (int i = t; i < 432; i += 256) {
            int oc = i / 9, p = i % 9;
            u64 m2 = 0, m3 = 0;
            for (int c = 0; c < 48; ++c) {
                if (w2[oc*432 + c*9 + p] > 0.0f) m2 |= (1ull << c);
                if (w3[oc*432 + c*9 + p] > 0.0f) m3 |= (1ull << c);
            }
            W2P[i] = m2;
            W3P[i] = m3;
        }
        for (int i = t; i < 205; i += 256) {
            int o = i / 41, j = i % 41;
            u64 m = 0;
            for (int l = 0; l < 64; ++l) {
                int k = j*64 + l;
                if (k < 2592 && wfc[o*2592 + k] > 0.0f) m |= (1ull << l);
            }
            WFCP[i] = m;
        }
    } else if (blk == 1) {
        for (int i = t; i < 2304; i += 256) stats[i] = 0;
    }
    __threadfence();
    grid.sync();

    // ======== stage 1: binx -> xb1, conv1, pool -> P1, stats1 ========
    {
        u8*  bitsb = (u8*)(smem + 2432);    // 2160
        u16* As1   = (u16*)(smem + 4608);   // 180
        int* cmap  = (int*)(smem + 4976);   // s8 [48][192B] = 2304 ints
        for (int b = blk; b < 4096; b += nblk) {
            const float4* xp = (const float4*)(x + (size_t)b*2160);
            float4* xo = (float4*)(dout + XB1_OFF + (size_t)b*2160);
            for (int j = t; j < 540; j += 256) {
                float4 v = xp[j];
                float4 o;
                o.x = fsign(v.x); o.y = fsign(v.y); o.z = fsign(v.z); o.w = fsign(v.w);
                xo[j] = o;
                bitsb[4*j]   = v.x > 0.0f;
                bitsb[4*j+1] = v.y > 0.0f;
                bitsb[4*j+2] = v.z > 0.0f;
                bitsb[4*j+3] = v.w > 0.0f;
            }
            __syncthreads();
            if (t < 180) {
                u16 m = 0;
                #pragma unroll
                for (int c = 0; c < 12; ++c)
                    m |= ((u16)bitsb[c*180 + t]) << c;
                As1[t] = m;
            }
            __syncthreads();
            if (t < 180) {
                int y = t / 15, xx = t % 15;
                u16 tap[9], msk[9];
                int nv = 0;
                #pragma unroll
                for (int ky = 0; ky < 3; ++ky) {
                    #pragma unroll
                    for (int kx = 0; kx < 3; ++kx) {
                        int yy = y + ky - 1, xc = xx + kx - 1;
                        bool v = (yy >= 0 && yy < 12 && xc >= 0 && xc < 15);
                        int yl = min(max(yy, 0), 11), xl = min(max(xc, 0), 14);
                        tap[ky*3+kx] = As1[yl*15 + xl];
                        msk[ky*3+kx] = v ? (u16)0xFFFF : (u16)0;
                        nv += v ? 12 : 0;
                    }
                }
                u32 tq[5], mq[5];
                #pragma unroll
                for (int j = 0; j < 4; ++j) {
                    tq[j] = (u32)tap[2*j] | ((u32)tap[2*j+1] << 16);
                    mq[j] = (u32)msk[2*j] | ((u32)msk[2*j+1] << 16);
                }
                tq[4] = tap[8]; mq[4] = msk[8];
                s8* cb = (s8*)cmap;
                #pragma unroll 4
                for (int oc = 0; oc < 48; ++oc) {
                    int acc = 0;
                    #pragma unroll
                    for (int j = 0; j < 5; ++j)
                        acc += __popc((tq[j] ^ W1Q[oc*5 + j]) & mq[j]);
                    cb[oc*192 + y*16 + xx] = (s8)(nv - 2*acc);
                }
            }
            __syncthreads();
            if (t < 192) {
                int c = t >> 2, q = t & 3;
                int r0 = 3*q, nr = (q < 3) ? 3 : 2;
                int rowv[4][4];
                #pragma unroll
                for (int j = 0; j < 4; ++j)
                    if (j <= nr) {
                        #pragma unroll
                        for (int i = 0; i < 4; ++i)
                            rowv[j][i] = cmap[c*48 + (r0 + j)*4 + i];
                    }
                int sum = 0, sq = 0;
                u8* gp = P1g + (size_t)b*8448 + c*176;
                #pragma unroll
                for (int pr = 0; pr < 3; ++pr) {
                    if (pr < nr) {
                        int o0 = 0, o1 = 0, o2 = 0, o3 = 0;
                        #pragma unroll
                        for (int k = 0; k < 14; ++k) {
                            int a0 = (int)(s8)(rowv[pr][k>>2] >> (8*(k&3)));
                            int a1 = (int)(s8)(rowv[pr][(k+1)>>2] >> (8*((k+1)&3)));
                            int b0 = (int)(s8)(rowv[pr+1][k>>2] >> (8*(k&3)));
                            int b1 = (int)(s8)(rowv[pr+1][(k+1)>>2] >> (8*((k+1)&3)));
                            int mx = max(max(a0, a1), max(b0, b1));
                            sum += mx; sq += mx*mx;
                            int shl = 8*(k&3);
                            if ((k>>2) == 0) o0 |= (mx & 255) << shl;
                            else if ((k>>2) == 1) o1 |= (mx & 255) << shl;
                            else if ((k>>2) == 2) o2 |= (mx & 255) << shl;
                            else o3 |= (mx & 255) << shl;
                        }
                        *((int4*)(gp + (r0 + pr)*16)) = make_int4(o0, o1, o2, o3);
                    }
                }
                part[t] = make_int2(sum, sq);
            }
            __syncthreads();
            if (t < 48) {
                int s = 0, q = 0;
                #pragma unroll
                for (int k = 0; k < 4; ++k) { s += part[t*4+k].x; q += part[t*4+k].y; }
                int slot = b & 7;
                atomicAdd((u64*)&stats[t*8 + slot],        (u64)(long long)s);
                atomicAdd((u64*)&stats[(48 + t)*8 + slot], (u64)(long long)q);
            }
            __syncthreads();
        }
    }
    __threadfence();
    grid.sync();

    // ======== stage 2: BN1 -> xb2 + A2 masks + conv2 + stats2 ========
    {
        if (t < 48) {
            long long s = 0, q = 0;
            #pragma unroll
            for (int k = 0; k < 8; ++k) { s += stats[t*8 + k]; q += stats[(48 + t)*8 + k]; }
            double N = 630784.0;   // 4096*11*14
            double mean = (double)s / N;
            double var  = (double)q / N - mean*mean;
            double scale = (double)g1[t] / sqrt(var + 1e-5);
            sc[t] = (float)scale;
            sh[t] = (float)((double)b1[t] - mean*scale);
        }
        __syncthreads();
        u64*   As2 = (u64*)(smem + 2432);    // 154
        short* c2s = (short*)(smem + 3664);  // [48][108]
        for (int b = blk; b < 4096; b += nblk) {
            const u8* pb = P1g + (size_t)b*8448;
            float4* xo = (float4*)(dout + XB2_OFF + (size_t)b*7392);
            for (int i4 = t; i4 < 1848; i4 += 256) {
                int i = 4*i4;
                float r[4];
                #pragma unroll
                for (int k = 0; k < 4; ++k) {
                    int uk = i + k;
                    int c = uk / 154;
                    int s = uk - 154*c;
                    int row = s / 14;
                    int px = s - 14*row;
                    int v = (int)(s8)pb[c*176 + row*16 + px];
                    r[k] = fsign(sc[c]*(float)v + sh[c]);
                }
                float4 o; o.x = r[0]; o.y = r[1]; o.z = r[2]; o.w = r[3];
                xo[i4] = o;
            }
            if (t < 154) {
                int row = t / 14, px = t - 14*row;
                const u8* pbe = pb + row*16 + px;
                u64 m = 0;
                #pragma unroll
                for (int c = 0; c < 48; ++c)
                    if (sc[c]*(float)(s8)pbe[c*176] + sh[c] > 0.0f) m |= (1ull << c);
                As2[t] = m;
                A2[(size_t)b*154 + t] = m;
            }
            __syncthreads();
            if (t < 216) {
                int pos = (t < 108) ? t : (t - 108);
                int ocb = (t < 108) ? 0 : 24;
                int oy = pos / 12, ox = pos - 12*oy;
                u64 tap[9];
                #pragma unroll
                for (int ky = 0; ky < 3; ++ky)
                    #pragma unroll
                    for (int kx = 0; kx < 3; ++kx)
                        tap[ky*3+kx] = As2[(oy+ky)*14 + ox + kx];
                #pragma unroll 4
                for (int oc = ocb; oc < ocb + 24; ++oc) {
                    int acc = 0;
                    #pragma unroll
                    for (int k = 0; k < 9; ++k)
                        acc += __popcll(tap[k] ^ W2P[oc*9 + k]);
                    c2s[oc*108 + pos] = (short)(432 - 2*acc);
                }
            }
            __syncthreads();
            if (t < 192) {
                int c = t >> 2, q = t & 3;
                const int* ci = (const int*)(c2s + c*108);
                int sum = 0, sq = 0;
                for (int j = q; j < 54; j += 4) {
                    int v2 = ci[j];
                    int lo = (int)(short)v2, hi = v2 >> 16;
                    sum += lo + hi; sq += lo*lo + hi*hi;
                }
                part[t] = make_int2(sum, sq);
            }
            __syncthreads();
            if (t < 48) {
                int s = 0, q = 0;
                #pragma unroll
                for (int k = 0; k < 4; ++k) { s += part[t*4+k].x; q += part[t*4+k].y; }
                int slot = b & 7;
                atomicAdd((u64*)&stats[(96 + t)*8 + slot],  (u64)(long long)s);
                atomicAdd((u64*)&stats[(144 + t)*8 + slot], (u64)(long long)q);
            }
            __syncthreads();
        }
    }
    __threadfence();
    grid.sync();

    // ======== stage 3: conv2 recompute + BN2 -> xb3 + A3 + conv3 + pool -> P3 + stats3 ========
    {
        if (t < 48) {
            long long s = 0, q = 0;
            #pragma unroll
            for (int k = 0; k < 8; ++k) { s += stats[(96 + t)*8 + k]; q += stats[(144 + t)*8 + k]; }
            double N = 442368.0;   // 4096*9*12
            double mean = (double)s / N;
            double var  = (double)q / N - mean*mean;
            double scale = (double)g2[t] / sqrt(var + 1e-5);
            sc[t] = (float)scale;
            sh[t] = (float)((double)b2[t] - mean*scale);
        }
        __syncthreads();
        u64*   As2 = (u64*)(smem + 2432);     // 154
        short* c2s = (short*)(smem + 3664);   // [48][108]
        u64*   A3s = (u64*)(smem + 14032);    // 108
        short* cm  = (short*)(smem + 14896);  // [48][70]
        for (int b = blk; b < 4096; b += nblk) {
            if (t < 154) As2[t] = A2[(size_t)b*154 + t];
            __syncthreads();
            if (t < 216) {
                int pos = (t < 108) ? t : (t - 108);
                int ocb = (t < 108) ? 0 : 24;
                int oy = pos / 12, ox = pos - 12*oy;
                u64 tap[9];
                #pragma unroll
                for (int ky = 0; ky < 3; ++ky)
                    #pragma unroll
                    for (int kx = 0; kx < 3; ++kx)
                        tap[ky*3+kx] = As2[(oy+ky)*14 + ox + kx];
                #pragma unroll 4
                for (int oc = ocb; oc < ocb + 24; ++oc) {
                    int acc = 0;
                    #pragma unroll
                    for (int k = 0; k < 9; ++k)
                        acc += __popcll(tap[k] ^ W2P[oc*9 + k]);
                    c2s[oc*108 + pos] = (short)(432 - 2*acc);
                }
            }
            __syncthreads();
            float4* xo = (float4*)(dout + XB3_OFF + (size_t)b*5184);
            for (int i4 = t; i4 < 1296; i4 += 256) {
                int c = i4 / 27, s4 = i4 - 27*c;
                short4 v4 = *(const short4*)&c2s[c*108 + s4*4];
                float4 o;
                o.x = fsign(sc[c]*(float)v4.x + sh[c]);
                o.y = fsign(sc[c]*(float)v4.y + sh[c]);
                o.z = fsign(sc[c]*(float)v4.z + sh[c]);
                o.w = fsign(sc[c]*(float)v4.w + sh[c]);
                xo[i4] = o;
            }
            if (t < 108) {
                u64 m = 0;
                #pragma unroll
                for (int c = 0; c < 48; ++c)
                    if (sc[c]*(float)c2s[c*108 + t] + sh[c] > 0.0f) m |= (1ull << c);
                A3s[t] = m;
            }
            __syncthreads();
            if (t < 210) {
                int grp = (t < 70) ? 0 : ((t < 140) ? 1 : 2);
                int pos = t - grp*70;
                int ocb = grp*16;
                int oy = pos / 10, ox = pos - 10*oy;
                u64 tap[9];
                #pragma unroll
                for (int ky = 0; ky < 3; ++ky)
                    #pragma unroll
                    for (int kx = 0; kx < 3; ++kx)
                        tap[ky*3+kx] = A3s[(oy+ky)*12 + ox + kx];
                #pragma unroll 4
                for (int oc = ocb; oc < ocb + 16; ++oc) {
                    int acc = 0;
                    #pragma unroll
                    for (int k = 0; k < 9; ++k)
                        acc += __popcll(tap[k] ^ W3P[oc*9 + k]);
                    cm[oc*70 + pos] = (short)(432 - 2*acc);
                }
            }
            __syncthreads();
            if (t < 192) {
                int c = t >> 2, q = t & 3;
                int pr0 = (q < 2) ? 2*q : (q + 2);
                int npr = (q < 2) ? 2 : 1;
                int rowv[3][5];
                const int* cmi = (const int*)(cm + c*70);
                #pragma unroll
                for (int j = 0; j < 3; ++j)
                    if (j <= npr) {
                        #pragma unroll
                        for (int i = 0; i < 5; ++i)
                            rowv[j][i] = cmi[(pr0 + j)*5 + i];
                    }
                int sum = 0, sq = 0;
                int* gp = P3i + (size_t)b*1440 + c*30;
                #pragma unroll
                for (int pr = 0; pr < 2; ++pr) {
                    if (pr < npr) {
                        int o[5] = {0, 0, 0, 0, 0};
                        #pragma unroll
                        for (int k = 0; k < 9; ++k) {
                            int a0 = sh16(rowv[pr][k>>1], k&1);
                            int a1 = sh16(rowv[pr][(k+1)>>1], (k+1)&1);
                            int b0 = sh16(rowv[pr+1][k>>1], k&1);
                            int b1 = sh16(rowv[pr+1][(k+1)>>1], (k+1)&1);
                            int mx = max(max(a0, a1), max(b0, b1));
                            sum += mx; sq += mx*mx;
                            o[k>>1] |= (mx & 0xffff) << (16*(k&1));
                        }
                        #pragma unroll
                        for (int j = 0; j < 5; ++j) gp[(pr0 + pr)*5 + j] = o[j];
                    }
                }
                part[t] = make_int2(sum, sq);
            }
            __syncthreads();
            if (t < 48) {
                int s = 0, q = 0;
                #pragma unroll
                for (int k = 0; k < 4; ++k) { s += part[t*4+k].x; q += part[t*4+k].y; }
                int slot = b & 7;
                atomicAdd((u64*)&stats[(192 + t)*8 + slot], (u64)(long long)s);
                atomicAdd((u64*)&stats[(240 + t)*8 + slot], (u64)(long long)q);
            }
            __syncthreads();
        }
    }
    __threadfence();
    grid.sync();

    // ======== stage 4: BN3 -> fb + FC ========
    {
        if (t < 48) {
            long long s = 0, q = 0;
            #pragma unroll
            for (int k = 0; k < 8; ++k) { s += stats[(192 + t)*8 + k]; q += stats[(240 + t)*8 + k]; }
            double N = 221184.0;   // 4096*6*9
            double mean = (double)s / N;
            double var  = (double)q / N - mean*mean;
            double scale = (double)g3[t] / sqrt(var + 1e-5);
            sc[t] = (float)scale;
            sh[t] = (float)((double)b3[t] - mean*scale);
        }
        __syncthreads();
        int* smP = (int*)(smem + 2432);     // [1440]
        u8*  nib = (u8*)(smem + 8192);      // [648]
        u64* fbb = (u64*)(smem + 8840);     // [41]
        for (int b = blk; b < 4096; b += nblk) {
            const int4* p4 = (const int4*)(P3i + (size_t)b*1440);
            for (int i = t; i < 360; i += 256) ((int4*)smP)[i] = p4[i];
            __syncthreads();
            const short* smS = (const short*)smP;
            float4* fo = (float4*)(dout + FB_OFF + (size_t)b*2592);
            for (int i4 = t; i4 < 648; i4 += 256) {
                int i = 4*i4;
                float r[4];
                unsigned n = 0;
                #pragma unroll
                for (int k = 0; k < 4; ++k) {
                    int idx = i + k;
                    int c = idx / 54, s = idx - 54*c;
                    int row = s / 9, px = s - 9*row;
                    float bn = sc[c]*(float)smS[c*60 + row*10 + px] + sh[c];
                    r[k] = fsign(bn);
                    if (bn > 0.0f) n |= (1u << k);
                }
                float4 o; o.x = r[0]; o.y = r[1]; o.z = r[2]; o.w = r[3];
                fo[i4] = o;
                nib[i4] = (u8)n;
            }
            __syncthreads();
            if (t < 41) {
                u64 m = 0;
                #pragma unroll
                for (int k = 0; k < 16; ++k) {
                    int j = t*16 + k;
                    if (j < 648) m |= ((u64)nib[j]) << (4*k);
                }
                fbb[t] = m;
            }
            __syncthreads();
            if (t < 5) {
                const u64* Wf = WFCP + t*41;
                int acc = 0;
                #pragma unroll
                for (int j = 0; j < 41; ++j) acc += __popcll(fbb[j] ^ Wf[j]);
                dout[OUT_OFF + b*5 + t] = (float)(2592 - 2*acc);
            }
            __syncthreads();
        }
    }
}

extern "C" void kernel_launch(void* const* d_in, const int* in_sizes, int n_in,
                              void* d_out, int out_size, void* d_ws, size_t ws_size,
                              hipStream_t stream) {
    const float* x   = (const float*)d_in[0];
    const float* w1  = (const float*)d_in[1];
    const float* g1  = (const float*)d_in[2];
    const float* b1  = (const float*)d_in[3];
    const float* w2  = (const float*)d_in[4];
    const float* g2  = (const float*)d_in[5];
    const float* b2  = (const float*)d_in[6];
    const float* w3  = (const float*)d_in[7];
    const float* g3  = (const float*)d_in[8];
    const float* b3  = (const float*)d_in[9];
    const float* wfc = (const float*)d_in[10];
    float* out = (float*)d_out;
    char* ws = (char*)d_ws;

    long long* stats = (long long*)(ws + WS_STATS);
    u32*       W1Q   = (u32*)(ws + WS_W1Q);
    u64*       W2P   = (u64*)(ws + WS_W2P);
    u64*       W3P   = (u64*)(ws + WS_W3P);
    u64*       WFCP  = (u64*)(ws + WS_WFCP);
    u64*       A2    = (u64*)(ws + WS_A2);
    u8*        P1g   = (u8*)(ws + WS_P1);
    int*       P3i   = (int*)(ws + WS_P1);   // overlays P1 (dead after stage 2)

    // Query real co-residency and size the cooperative grid to it.
    int perCU = 0;
    hipError_t qe = hipOccupancyMaxActiveBlocksPerMultiprocessor(&perCU, kfull, 256, 0);
    int gridBlocks = (qe == hipSuccess && perCU > 0) ? perCU * 256 : 256;
    if (gridBlocks > 1024) gridBlocks = 1024;
    if (gridBlocks < 2)    gridBlocks = 2;

    void* args[] = {
        (void*)&x, (void*)&w1, (void*)&g1, (void*)&b1,
        (void*)&w2, (void*)&g2, (void*)&b2,
        (void*)&w3, (void*)&g3, (void*)&b3,
        (void*)&wfc, (void*)&out, (void*)&stats,
        (void*)&W1Q, (void*)&W2P, (void*)&W3P,
        (void*)&WFCP, (void*)&A2, (void*)&P1g, (void*)&P3i
    };
    hipLaunchCooperativeKernel((void*)kfull, dim3(gridBlocks), dim3(256),
                               args, 0, stream);
}